// Round 10
// baseline (34.173 us; speedup 1.0000x reference)
//
#include <hip/hip_runtime.h>
#include <math.h>

// Problem constants
constexpr int Bn = 512;
constexpr int Tn = 512;
constexpr int Dn = 128;
constexpr int Hn = 128;
constexpr int NT = 512;       // threads per block (one block per batch)
constexpr int NW = NT / 64;   // 8 waves

// Sum across the 16-lane row group via DPP row rotations (pure VALU, no LDS).
__device__ __forceinline__ float rowsum16(float x) {
    int v;
    v = __float_as_int(x);
    x += __int_as_float(__builtin_amdgcn_update_dpp(0, v, 0x121, 0xF, 0xF, true)); // row_ror:1
    v = __float_as_int(x);
    x += __int_as_float(__builtin_amdgcn_update_dpp(0, v, 0x122, 0xF, 0xF, true)); // row_ror:2
    v = __float_as_int(x);
    x += __int_as_float(__builtin_amdgcn_update_dpp(0, v, 0x124, 0xF, 0xF, true)); // row_ror:4
    v = __float_as_int(x);
    x += __int_as_float(__builtin_amdgcn_update_dpp(0, v, 0x128, 0xF, 0xF, true)); // row_ror:8
    return x;
}

__global__ __launch_bounds__(NT, 6)   // 6 waves/EU -> 3 blocks/CU (24 waves/CU), VGPR cap 85
void single_attn_fused4(const float* __restrict__ input,   // [B,T,D]
                        const int*   __restrict__ mask,    // [B,T]
                        const float* __restrict__ Wt,      // [D,H]
                        const float* __restrict__ Wx,      // [D,H]
                        const float* __restrict__ rate,    // [1]
                        float* __restrict__ out_v,         // [B,D]
                        float* __restrict__ out_a)         // [B,T]
{
    const int b    = blockIdx.x;
    const int tid  = threadIdx.x;
    const int lane = tid & 63;
    const int wid  = tid >> 6;
    const int seg  = tid & 15;     // 16 lanes per row; floats seg*8..seg*8+7
    const int rg   = tid >> 4;     // row group 0..31
    const float* __restrict__ inb = input + (size_t)b * Tn * Dn;
    const float4* __restrict__ in4 = (const float4*)inb;

    __shared__ float ps[Tn];          // 2 KB unnormalized weights
    __shared__ int   msk[Tn];         // 2 KB
    __shared__ float lv[Dn];
    __shared__ float qs[Hn];
    __shared__ float us[Dn];
    __shared__ float redl[NW];
    __shared__ int   ired[NW];
    __shared__ float vp[32 * 132];    // 16.9 KB v partials

    // ---- prologue: last_idx, lv, q = lv@Wt, u = Wx@q ----
    const int mv = mask[(size_t)b * Tn + tid];
    msk[tid] = mv;
    {
        int ms = mv;
        #pragma unroll
        for (int off = 32; off > 0; off >>= 1) ms += __shfl_down(ms, off, 64);
        if (lane == 0) ired[wid] = ms;
    }
    __syncthreads();
    int last_idx;
    {
        int s = 0;
        #pragma unroll
        for (int w = 0; w < NW; ++w) s += ired[w];
        last_idx = s - 1;
    }
    if (tid < Dn) lv[tid] = inb[(size_t)last_idx * Dn + tid];
    __syncthreads();
    if (tid < Hn) {
        float a0 = 0.f, a1 = 0.f;
        #pragma unroll 16
        for (int d0 = 0; d0 < Dn; d0 += 2) {
            a0 = fmaf(lv[d0],     Wt[d0 * Hn + tid],       a0);
            a1 = fmaf(lv[d0 + 1], Wt[(d0 + 1) * Hn + tid], a1);
        }
        qs[tid] = a0 + a1;
    }
    __syncthreads();
    if (tid < Dn) {
        float a0 = 0.f, a1 = 0.f;
        const float* wxr = Wx + tid * Hn;
        #pragma unroll 16
        for (int h = 0; h < Hn; h += 2) {
            a0 = fmaf(wxr[h],     qs[h],     a0);
            a1 = fmaf(wxr[h + 1], qs[h + 1], a1);
        }
        us[tid] = a0 + a1;
    }
    __syncthreads();

    const float srate = 1.f / (1.f + __expf(-rate[0]));
    const float4 u4a = ((const float4*)us)[seg * 2];
    const float4 u4b = ((const float4*)us)[seg * 2 + 1];

    // ---- fused streaming pass: dot -> p -> weighted accumulate, input read ONCE ----
    // e = relu(sig/den) in [0, ~1.45] (den >= sigmoid(0.8)*log(2.72) ~= 0.69),
    // so exp(e) <= 4.3: softmax needs no max subtraction.
    float4 v0 = make_float4(0.f, 0.f, 0.f, 0.f);
    float4 v1 = make_float4(0.f, 0.f, 0.f, 0.f);
    float  lsum = 0.f;

    #pragma unroll 4
    for (int it = 0; it < 16; ++it) {
        const int row = it * 32 + rg;              // == t
        const float4 x0 = in4[row * 32 + seg * 2];
        const float4 x1 = in4[row * 32 + seg * 2 + 1];
        float dot = x0.x * u4a.x + x0.y * u4a.y + x0.z * u4a.z + x0.w * u4a.w;
        dot = fmaf(x1.x, u4b.x, dot);
        dot = fmaf(x1.y, u4b.y, dot);
        dot = fmaf(x1.z, u4b.z, dot);
        dot = fmaf(x1.w, u4b.w, dot);
        dot = rowsum16(dot);                       // DPP reduce: no DS ops
        const float sig = 1.f / (1.f + __expf(-dot));
        const float den = srate * (__logf(2.72f + (1.f - sig)) * (float)(Tn - row));
        const float e   = fmaxf(sig / den, 0.f);
        const float p   = msk[row] ? __expf(e) : 0.f;
        v0.x = fmaf(p, x0.x, v0.x);
        v0.y = fmaf(p, x0.y, v0.y);
        v0.z = fmaf(p, x0.z, v0.z);
        v0.w = fmaf(p, x0.w, v0.w);
        v1.x = fmaf(p, x1.x, v1.x);
        v1.y = fmaf(p, x1.y, v1.y);
        v1.z = fmaf(p, x1.z, v1.z);
        v1.w = fmaf(p, x1.w, v1.w);
        if (seg == 0) { ps[row] = p; lsum += p; }
    }

    // stash v partials (16B-aligned: rg*132 + seg*8)
    {
        float* vr = vp + rg * 132 + seg * 8;
        ((float4*)vr)[0] = v0;
        ((float4*)vr)[1] = v1;
    }
    // block-reduce l (nonzero only on seg==0 lanes)
    float ls = lsum;
    #pragma unroll
    for (int off = 32; off > 0; off >>= 1) ls += __shfl_down(ls, off, 64);
    if (lane == 0) redl[wid] = ls;
    __syncthreads();   // vp + ps + redl visible

    float l = 0.f;
    #pragma unroll
    for (int w = 0; w < NW; ++w) l += redl[w];
    const float inv_l = 1.f / l;

    out_a[(size_t)b * Tn + tid] = ps[tid] * inv_l;

    if (tid < Dn) {
        float s = 0.f;
        #pragma unroll
        for (int r = 0; r < 32; ++r) s += vp[r * 132 + tid];
        out_v[(size_t)b * Dn + tid] = s * inv_l;
    }
}

extern "C" void kernel_launch(void* const* d_in, const int* in_sizes, int n_in,
                              void* d_out, int out_size, void* d_ws, size_t ws_size,
                              hipStream_t stream) {
    const float* input = (const float*)d_in[0];   // [B,T,D]
    const int*   mask  = (const int*)d_in[1];     // [B,T]
    const float* Wt    = (const float*)d_in[2];   // [D,H]
    const float* Wx    = (const float*)d_in[3];   // [D,H]
    const float* rate  = (const float*)d_in[4];   // [1]

    float* out   = (float*)d_out;
    float* out_v = out;                 // [B,D]  (return order: v, a)
    float* out_a = out + Bn * Dn;       // [B,T]

    single_attn_fused4<<<Bn, NT, 0, stream>>>(input, mask, Wt, Wx, rate, out_v, out_a);
}